// Round 1
// baseline (421.788 us; speedup 1.0000x reference)
//
#include <hip/hip_runtime.h>
#include <math.h>

// Problem constants
#define EMBED   2048
#define NHEADS  16
#define HD      128
#define S_TOT   4096
#define BATCH   64

typedef __attribute__((ext_vector_type(8))) short short8v;
typedef __attribute__((ext_vector_type(4))) short short4v;
typedef __attribute__((ext_vector_type(2))) short short2v;
typedef __attribute__((ext_vector_type(4))) float floatx4;

// fp32 -> bf16, round-to-nearest-even
__device__ __forceinline__ unsigned short f2bf(float f) {
    unsigned u = __builtin_bit_cast(unsigned, f);
    u += 0x7fffu + ((u >> 16) & 1u);
    return (unsigned short)(u >> 16);
}

// DPP row-rotate (within 16-lane rows) move; CTRL = 0x120 + N for row_ror:N
template <int CTRL>
__device__ __forceinline__ float dppf(float x) {
    int r = __builtin_amdgcn_mov_dpp(__builtin_bit_cast(int, x), CTRL, 0xF, 0xF, false);
    return __builtin_bit_cast(float, r);
}
__device__ __forceinline__ float rowmax16(float v) {
    v = fmaxf(v, dppf<0x121>(v));
    v = fmaxf(v, dppf<0x122>(v));
    v = fmaxf(v, dppf<0x124>(v));
    v = fmaxf(v, dppf<0x128>(v));
    return v;
}
__device__ __forceinline__ float rowsum16(float v) {
    v += dppf<0x121>(v);
    v += dppf<0x122>(v);
    v += dppf<0x124>(v);
    v += dppf<0x128>(v);
    return v;
}

// ---------------------------------------------------------------------------
// K1: fused QKV projection. out = x @ [Wq|Wk|Wv] + bias, M=64, N=2304, K=2048
// grid (36 n-tiles of 64 cols, 32 k-splits of 64), block 256.
// 2 cols/thread halves LDS re-read volume; 1152 blocks => ~4.5 blocks/CU.
// Atomic accumulate into zero-initialized buffers; ksplit 0 folds bias.
// ---------------------------------------------------------------------------
__launch_bounds__(256)
__global__ void k1_qkv(const float* __restrict__ x,
                       const float* __restrict__ Wq, const float* __restrict__ bq,
                       const float* __restrict__ Wk, const float* __restrict__ bk,
                       const float* __restrict__ Wv, const float* __restrict__ bv,
                       float* __restrict__ qbuf, float* __restrict__ knew,
                       float* __restrict__ vnew) {
    const int tx = threadIdx.x & 31;
    const int ty = threadIdx.x >> 5;   // 0..7
    const int col0 = blockIdx.x * 64;  // 0..2240
    const int kb = blockIdx.y * 64;    // 0..1984

    const float* W; const float* bias; float* out; int ldW; int cbase;
    if (col0 < 2048)       { W = Wq; bias = bq; out = qbuf; ldW = 2048; cbase = col0; }
    else if (col0 < 2176)  { W = Wk; bias = bk; out = knew; ldW = 128;  cbase = col0 - 2048; }
    else                   { W = Wv; bias = bv; out = vnew; ldW = 128;  cbase = col0 - 2176; }
    const int c0 = cbase + tx;
    const int c1 = cbase + 32 + tx;

    __shared__ __align__(16) float xs[64][68];   // 64 rows x 64 k, pad to 68

    // stage x[0..64][kb..kb+64], fully coalesced
    #pragma unroll
    for (int i = 0; i < 4; ++i) {
        int c = threadIdx.x + i * 256;   // float4 chunk id 0..1023
        int r = c >> 4;
        int cc = (c & 15) << 2;
        *(float4*)&xs[r][cc] = *(const float4*)(x + (size_t)r * EMBED + kb + cc);
    }

    float acc0[8] = {0, 0, 0, 0, 0, 0, 0, 0};
    float acc1[8] = {0, 0, 0, 0, 0, 0, 0, 0};
    __syncthreads();

    #pragma unroll 4
    for (int kk = 0; kk < 64; kk += 4) {
        float w00 = W[(size_t)(kb + kk + 0) * ldW + c0];
        float w01 = W[(size_t)(kb + kk + 1) * ldW + c0];
        float w02 = W[(size_t)(kb + kk + 2) * ldW + c0];
        float w03 = W[(size_t)(kb + kk + 3) * ldW + c0];
        float w10 = W[(size_t)(kb + kk + 0) * ldW + c1];
        float w11 = W[(size_t)(kb + kk + 1) * ldW + c1];
        float w12 = W[(size_t)(kb + kk + 2) * ldW + c1];
        float w13 = W[(size_t)(kb + kk + 3) * ldW + c1];
        #pragma unroll
        for (int j = 0; j < 8; ++j) {
            float4 xv = *(const float4*)&xs[ty + (j << 3)][kk];
            acc0[j] = fmaf(xv.x, w00, acc0[j]);
            acc0[j] = fmaf(xv.y, w01, acc0[j]);
            acc0[j] = fmaf(xv.z, w02, acc0[j]);
            acc0[j] = fmaf(xv.w, w03, acc0[j]);
            acc1[j] = fmaf(xv.x, w10, acc1[j]);
            acc1[j] = fmaf(xv.y, w11, acc1[j]);
            acc1[j] = fmaf(xv.z, w12, acc1[j]);
            acc1[j] = fmaf(xv.w, w13, acc1[j]);
        }
    }
    if (blockIdx.y == 0) {
        float b0 = bias[c0], b1 = bias[c1];
        #pragma unroll
        for (int j = 0; j < 8; ++j) { acc0[j] += b0; acc1[j] += b1; }
    }
    #pragma unroll
    for (int j = 0; j < 8; ++j) {
        atomicAdd(&out[(size_t)(ty + (j << 3)) * ldW + c0], acc0[j]);
        atomicAdd(&out[(size_t)(ty + (j << 3)) * ldW + c1], acc1[j]);
    }
}

// ---------------------------------------------------------------------------
// K2: flash-decode attention partials (split-KV).
// grid (16 chunks, 64 batches) = 1024 blocks (4/CU resident), block 256.
// Wave w owns 64 slots (2 steps of 32). LDS 37888 B:
//   per wave: K tile [16][136] bf16 (P [16][40] ALIASED on top of it),
//             V^T tile [64][40] bf16. q fragments come straight from global.
// Wave pairs merge in-block -> 32 partials per (b,h), same ws layout as before.
// ---------------------------------------------------------------------------
#define KT_SH (16 * 136)
#define VT_SH (64 * 40)
#define WAVE_SH (KT_SH + VT_SH)   // 4736 shorts = 9472 B per wave

__launch_bounds__(256, 4)
__global__ void k2_attn(const float* __restrict__ qbuf,
                        const float* __restrict__ kcache,
                        const float* __restrict__ vcache,
                        const float* __restrict__ knew,
                        const float* __restrict__ vnew,
                        const int* __restrict__ cpos,
                        float* __restrict__ part_o,   // [B][32][16][128]
                        float* __restrict__ part_ml)  // [B][32][16][2]
{
    const int b = blockIdx.y;
    const int chunk = blockIdx.x;      // 0..15
    const int tid = threadIdx.x;
    const int w = tid >> 6;
    const int lane = tid & 63;
    const int quad = lane >> 4;
    const int lm = lane & 15;
    const int pos = cpos[b];

    __shared__ __align__(16) short smem[4 * WAVE_SH];   // 37888 B -> 4 blocks/CU
    short* kt = smem + w * WAVE_SH;
    short* vt = kt + KT_SH;
    short* pt = kt;   // alias: P written only after K of the step is consumed

    // ---- q A-fragments straight from global: A[m=lm][k=quad*8+j], K-steps t*32
    short8v aq[4];
    {
        const float* qsrc = qbuf + (size_t)b * EMBED + lm * HD + quad * 8;
        const float s = 0.08838834764831845f;  // 1/sqrt(128)
        #pragma unroll
        for (int t = 0; t < 4; ++t) {
            float4 a = *(const float4*)(qsrc + t * 32);
            float4 c = *(const float4*)(qsrc + t * 32 + 4);
            short8v pk;
            pk[0] = f2bf(a.x * s); pk[1] = f2bf(a.y * s);
            pk[2] = f2bf(a.z * s); pk[3] = f2bf(a.w * s);
            pk[4] = f2bf(c.x * s); pk[5] = f2bf(c.y * s);
            pk[6] = f2bf(c.z * s); pk[7] = f2bf(c.w * s);
            aq[t] = pk;
        }
    }

    float m_run[4] = {-INFINITY, -INFINITY, -INFINITY, -INFINITY};
    float l_run[4] = {0, 0, 0, 0};
    floatx4 oacc[8];
    #pragma unroll
    for (int i = 0; i < 8; ++i) oacc[i] = (floatx4){0, 0, 0, 0};

    const int sbase = chunk * 256 + w * 64;

    for (int st = 0; st < 2; ++st) {
        const int st0 = sbase + st * 32;
        floatx4 sc2[2];
        // ---- QK for two 16-slot tiles
        #pragma unroll
        for (int half = 0; half < 2; ++half) {
            const int s0 = st0 + half * 16;
            float4 tmp[8];
            #pragma unroll
            for (int i = 0; i < 8; ++i) {
                int f = i * 64 + lane;
                tmp[i] = *(const float4*)(kcache +
                    ((size_t)b * S_TOT + s0 + (f >> 5)) * HD + (f & 31) * 4);
            }
            #pragma unroll
            for (int i = 0; i < 8; ++i) {
                int f = i * 64 + lane;
                short4v pk;
                pk[0] = f2bf(tmp[i].x); pk[1] = f2bf(tmp[i].y);
                pk[2] = f2bf(tmp[i].z); pk[3] = f2bf(tmp[i].w);
                *(short4v*)&kt[(f >> 5) * 136 + (f & 31) * 4] = pk;
            }
            // substitute k_new at cache position (wave-uniform branch)
            const int pr = pos - s0;
            if (pr >= 0 && pr < 16) {
                float2 kv = *(const float2*)(knew + b * HD + lane * 2);
                short2v p2; p2[0] = f2bf(kv.x); p2[1] = f2bf(kv.y);
                *(short2v*)&kt[pr * 136 + lane * 2] = p2;
            }
            floatx4 s = {0, 0, 0, 0};
            #pragma unroll
            for (int t = 0; t < 4; ++t) {
                short8v bk_ = *(short8v*)&kt[lm * 136 + t * 32 + quad * 8];
                s = __builtin_amdgcn_mfma_f32_16x16x32_bf16(aq[t], bk_, s, 0, 0, 0);
            }
            sc2[half] = s;
        }
        // ---- online softmax over the 32 slots (rows = heads, via DPP reduce)
        float alpha[4];
        #pragma unroll
        for (int r = 0; r < 4; ++r) {
            float mt = rowmax16(fmaxf(sc2[0][r], sc2[1][r]));
            float mn = fmaxf(m_run[r], mt);
            alpha[r] = __expf(m_run[r] - mn);
            m_run[r] = mn;
            float pA = __expf(sc2[0][r] - mn);
            float pB = __expf(sc2[1][r] - mn);
            float ss = rowsum16(pA + pB);
            l_run[r] = l_run[r] * alpha[r] + ss;
            pt[(quad * 4 + r) * 40 + lm]      = (short)f2bf(pA);
            pt[(quad * 4 + r) * 40 + 16 + lm] = (short)f2bf(pB);
        }
        #pragma unroll
        for (int dt = 0; dt < 8; ++dt) {
            oacc[dt][0] *= alpha[0]; oacc[dt][1] *= alpha[1];
            oacc[dt][2] *= alpha[2]; oacc[dt][3] *= alpha[3];
        }
        // P A-fragment: A[m=h=lane&15][k=slot=quad*8+j]
        short8v ap = *(short8v*)&pt[lm * 40 + quad * 8];

        // ---- PV in two d-halves (vT staged transposed: vt[d_local][slot])
        #pragma unroll
        for (int p = 0; p < 2; ++p) {
            const int sg = lane & 7;     // slot group (4 slots)
            const int dgv = lane >> 3;   // 8 d-groups
            #pragma unroll
            for (int i = 0; i < 2; ++i) {
                int dl = dgv * 4 + i * 32;        // local d 0..60
                int dglob = p * 64 + dl;
                const float* vb = vcache + ((size_t)b * S_TOT + st0 + sg * 4) * HD + dglob;
                float4 r0 = *(const float4*)(vb + 0 * HD);
                float4 r1 = *(const float4*)(vb + 1 * HD);
                float4 r2 = *(const float4*)(vb + 2 * HD);
                float4 r3 = *(const float4*)(vb + 3 * HD);
                short4v p0, p1, p2, p3;
                p0[0]=f2bf(r0.x); p0[1]=f2bf(r1.x); p0[2]=f2bf(r2.x); p0[3]=f2bf(r3.x);
                p1[0]=f2bf(r0.y); p1[1]=f2bf(r1.y); p1[2]=f2bf(r2.y); p1[3]=f2bf(r3.y);
                p2[0]=f2bf(r0.z); p2[1]=f2bf(r1.z); p2[2]=f2bf(r2.z); p2[3]=f2bf(r3.z);
                p3[0]=f2bf(r0.w); p3[1]=f2bf(r1.w); p3[2]=f2bf(r2.w); p3[3]=f2bf(r3.w);
                *(short4v*)&vt[(dl + 0) * 40 + sg * 4] = p0;
                *(short4v*)&vt[(dl + 1) * 40 + sg * 4] = p1;
                *(short4v*)&vt[(dl + 2) * 40 + sg * 4] = p2;
                *(short4v*)&vt[(dl + 3) * 40 + sg * 4] = p3;
            }
            // substitute v_new column (wave-uniform branch)
            const int prs = pos - st0;
            if (prs >= 0 && prs < 32) {
                float vvn = vnew[b * HD + p * 64 + lane];
                vt[lane * 40 + prs] = (short)f2bf(vvn);
            }
            #pragma unroll
            for (int dq = 0; dq < 4; ++dq) {
                int dt = p * 4 + dq;
                short8v bv_ = *(short8v*)&vt[(dq * 16 + lm) * 40 + quad * 8];
                oacc[dt] = __builtin_amdgcn_mfma_f32_16x16x32_bf16(ap, bv_, oacc[dt], 0, 0, 0);
            }
        }
    }

    // ---- merge wave pairs (0<-1, 2<-3) via dead LDS; keeps 32 partials/(b,h)
    __syncthreads();
    float* pool = (float*)smem;        // 2 * 2080 floats = 16640 B << 37888
    const int hr = quad * 4;
    if (w & 1) {
        float* dst = pool + (w >> 1) * 2080;
        if (lm == 0) {
            #pragma unroll
            for (int r = 0; r < 4; ++r) { dst[hr + r] = m_run[r]; dst[16 + hr + r] = l_run[r]; }
        }
        #pragma unroll
        for (int dt = 0; dt < 8; ++dt)
            #pragma unroll
            for (int r = 0; r < 4; ++r)
                dst[32 + (hr + r) * 128 + dt * 16 + lm] = oacc[dt][r];
    }
    __syncthreads();
    if ((w & 1) == 0) {
        float* src = pool + (w >> 1) * 2080;
        float a1[4], a2[4];
        #pragma unroll
        for (int r = 0; r < 4; ++r) {
            float m2 = src[hr + r], l2 = src[16 + hr + r];
            float M = fmaxf(m_run[r], m2);
            a1[r] = __expf(m_run[r] - M);
            a2[r] = __expf(m2 - M);
            l_run[r] = l_run[r] * a1[r] + l2 * a2[r];
            m_run[r] = M;
        }
        #pragma unroll
        for (int dt = 0; dt < 8; ++dt)
            #pragma unroll
            for (int r = 0; r < 4; ++r)
                oacc[dt][r] = oacc[dt][r] * a1[r] +
                              src[32 + (hr + r) * 128 + dt * 16 + lm] * a2[r];

        const int cw = chunk * 2 + (w >> 1);
        float* po = part_o + (size_t)(b * 32 + cw) * 16 * 128;
        #pragma unroll
        for (int dt = 0; dt < 8; ++dt)
            #pragma unroll
            for (int r = 0; r < 4; ++r)
                po[(hr + r) * 128 + dt * 16 + lm] = oacc[dt][r];
        if (lm < 2) {
            #pragma unroll
            for (int r = 0; r < 4; ++r) {
                float v = (lm == 0) ? m_run[r] : l_run[r];
                part_ml[((size_t)(b * 32 + cw) * 16 + hr + r) * 2 + lm] = v;
            }
        }
    }
}

// ---------------------------------------------------------------------------
// K3: combine 32 partials per (b,h) -> attn[b][h*128+d]
// grid (16 heads, 64 batches), block 128 (thread = d). Fully unrolled with
// 4 independent accumulators so all 32 strided partial loads are in flight.
// ---------------------------------------------------------------------------
__launch_bounds__(128)
__global__ void k3_combine(const float* __restrict__ part_o,
                           const float* __restrict__ part_ml,
                           float* __restrict__ attn) {
    const int h = blockIdx.x, b = blockIdx.y, d = threadIdx.x;
    __shared__ float sm[32], sl[32];
    if (threadIdx.x < 32) {
        sm[threadIdx.x] = part_ml[((size_t)(b * 32 + threadIdx.x) * 16 + h) * 2 + 0];
        sl[threadIdx.x] = part_ml[((size_t)(b * 32 + threadIdx.x) * 16 + h) * 2 + 1];
    }
    __syncthreads();
    float M = -INFINITY;
    #pragma unroll
    for (int c = 0; c < 32; ++c) M = fmaxf(M, sm[c]);
    float co[32];
    float L = 0.f;
    #pragma unroll
    for (int c = 0; c < 32; ++c) {
        co[c] = __expf(sm[c] - M);
        L += co[c] * sl[c];
    }
    const float* base = part_o + ((size_t)(b * 32) * 16 + h) * 128 + d;
    float O0 = 0.f, O1 = 0.f, O2 = 0.f, O3 = 0.f;
    #pragma unroll
    for (int c = 0; c < 32; c += 4) {
        O0 += co[c + 0] * base[(size_t)(c + 0) * 2048];
        O1 += co[c + 1] * base[(size_t)(c + 1) * 2048];
        O2 += co[c + 2] * base[(size_t)(c + 2) * 2048];
        O3 += co[c + 3] * base[(size_t)(c + 3) * 2048];
    }
    attn[(size_t)b * EMBED + h * HD + d] = (O0 + O1 + O2 + O3) / L;
}

// ---------------------------------------------------------------------------
// K4: output projection. out = attn @ Wo + bo, M=64, N=2048, K=2048
// grid (32 n-tiles of 64 cols, 32 k-splits of 64), block 256, 2 cols/thread.
// Atomic into memset d_out.
// ---------------------------------------------------------------------------
__launch_bounds__(256)
__global__ void k4_proj(const float* __restrict__ attn,
                        const float* __restrict__ Wo, const float* __restrict__ bo,
                        float* __restrict__ out) {
    const int tx = threadIdx.x & 31;
    const int ty = threadIdx.x >> 5;
    const int c0 = blockIdx.x * 64 + tx;
    const int c1 = blockIdx.x * 64 + 32 + tx;
    const int kb = blockIdx.y * 64;

    __shared__ __align__(16) float xs[64][68];
    #pragma unroll
    for (int i = 0; i < 4; ++i) {
        int c = threadIdx.x + i * 256;
        int r = c >> 4;
        int cc = (c & 15) << 2;
        *(float4*)&xs[r][cc] = *(const float4*)(attn + (size_t)r * EMBED + kb + cc);
    }

    float acc0[8] = {0, 0, 0, 0, 0, 0, 0, 0};
    float acc1[8] = {0, 0, 0, 0, 0, 0, 0, 0};
    __syncthreads();

    #pragma unroll 4
    for (int kk = 0; kk < 64; kk += 4) {
        float w00 = Wo[(size_t)(kb + kk + 0) * EMBED + c0];
        float w01 = Wo[(size_t)(kb + kk + 1) * EMBED + c0];
        float w02 = Wo[(size_t)(kb + kk + 2) * EMBED + c0];
        float w03 = Wo[(size_t)(kb + kk + 3) * EMBED + c0];
        float w10 = Wo[(size_t)(kb + kk + 0) * EMBED + c1];
        float w11 = Wo[(size_t)(kb + kk + 1) * EMBED + c1];
        float w12 = Wo[(size_t)(kb + kk + 2) * EMBED + c1];
        float w13 = Wo[(size_t)(kb + kk + 3) * EMBED + c1];
        #pragma unroll
        for (int j = 0; j < 8; ++j) {
            float4 xv = *(const float4*)&xs[ty + (j << 3)][kk];
            acc0[j] = fmaf(xv.x, w00, acc0[j]);
            acc0[j] = fmaf(xv.y, w01, acc0[j]);
            acc0[j] = fmaf(xv.z, w02, acc0[j]);
            acc0[j] = fmaf(xv.w, w03, acc0[j]);
            acc1[j] = fmaf(xv.x, w10, acc1[j]);
            acc1[j] = fmaf(xv.y, w11, acc1[j]);
            acc1[j] = fmaf(xv.z, w12, acc1[j]);
            acc1[j] = fmaf(xv.w, w13, acc1[j]);
        }
    }
    if (blockIdx.y == 0) {
        float b0 = bo[c0], b1 = bo[c1];
        #pragma unroll
        for (int j = 0; j < 8; ++j) { acc0[j] += b0; acc1[j] += b1; }
    }
    #pragma unroll
    for (int j = 0; j < 8; ++j) {
        atomicAdd(&out[(size_t)(ty + (j << 3)) * EMBED + c0], acc0[j]);
        atomicAdd(&out[(size_t)(ty + (j << 3)) * EMBED + c1], acc1[j]);
    }
}

// ---------------------------------------------------------------------------
extern "C" void kernel_launch(void* const* d_in, const int* in_sizes, int n_in,
                              void* d_out, int out_size, void* d_ws, size_t ws_size,
                              hipStream_t stream) {
    (void)in_sizes; (void)n_in; (void)out_size; (void)ws_size;
    const float* x  = (const float*)d_in[0];
    const float* kc = (const float*)d_in[1];
    const float* vc = (const float*)d_in[2];
    const int*   cp = (const int*)d_in[3];
    const float* Wq = (const float*)d_in[4];
    const float* bq = (const float*)d_in[5];
    const float* Wk = (const float*)d_in[6];
    const float* bk = (const float*)d_in[7];
    const float* Wv = (const float*)d_in[8];
    const float* bv = (const float*)d_in[9];
    const float* Wo = (const float*)d_in[10];
    const float* bo = (const float*)d_in[11];
    float* out = (float*)d_out;
    float* ws  = (float*)d_ws;

    // ws layout (floats)
    float* qbuf = ws;                    // 131072
    float* knew = ws + 131072;           // 8192
    float* vnew = ws + 139264;           // 8192
    float* attn = ws + 147456;           // 131072
    float* po   = ws + 278528;           // 64*32*16*128 = 4194304
    float* pml  = ws + 4472832;          // 64*32*16*2   = 65536
    // total 4538368 floats = 18.2 MB

    hipMemsetAsync(qbuf, 0, 147456 * sizeof(float), stream);   // q/k_new/v_new
    hipMemsetAsync(out, 0, (size_t)BATCH * EMBED * sizeof(float), stream);

    k1_qkv<<<dim3(36, 32), 256, 0, stream>>>(x, Wq, bq, Wk, bk, Wv, bv, qbuf, knew, vnew);
    k2_attn<<<dim3(16, 64), 256, 0, stream>>>(qbuf, kc, vc, knew, vnew, cp, po, pml);
    k3_combine<<<dim3(16, 64), 128, 0, stream>>>(po, pml, attn);
    k4_proj<<<dim3(32, 32), 256, 0, stream>>>(attn, Wo, bo, out);
}

// Round 2
// 393.700 us; speedup vs baseline: 1.0713x; 1.0713x over previous
//
#include <hip/hip_runtime.h>
#include <math.h>

// Problem constants
#define EMBED   2048
#define NHEADS  16
#define HD      128
#define S_TOT   4096
#define BATCH   64

typedef __attribute__((ext_vector_type(8))) short short8v;
typedef __attribute__((ext_vector_type(4))) short short4v;
typedef __attribute__((ext_vector_type(4))) float floatx4;

// fp32 -> bf16, round-to-nearest-even
__device__ __forceinline__ unsigned short f2bf(float f) {
    unsigned u = __builtin_bit_cast(unsigned, f);
    u += 0x7fffu + ((u >> 16) & 1u);
    return (unsigned short)(u >> 16);
}

// ---------------------------------------------------------------------------
// K1: fused QKV projection partials. x @ [Wq|Wk|Wv], M=64, N=2304, K=2048.
// grid (18 n-tiles of 128 cols, 16 k-splits of 128), block 256, 4 cols/thread
// (float4 W loads). Non-atomic: writes kp[split][64][2304]; k1b reduces.
// ---------------------------------------------------------------------------
__launch_bounds__(256)
__global__ void k1_qkv(const float* __restrict__ x,
                       const float* __restrict__ Wq, const float* __restrict__ Wk,
                       const float* __restrict__ Wv, float* __restrict__ kp) {
    const int tx = threadIdx.x & 31;
    const int ty = threadIdx.x >> 5;   // 0..7
    const int col0 = blockIdx.x * 128; // 0..2176
    const int kb = blockIdx.y * 128;   // 0..1920

    const float* W; int ldW; int cbase;
    if (col0 < 2048)       { W = Wq; ldW = 2048; cbase = col0; }
    else if (col0 == 2048) { W = Wk; ldW = 128;  cbase = 0; }
    else                   { W = Wv; ldW = 128;  cbase = 0; }
    const int c4 = cbase + tx * 4;

    __shared__ __align__(16) float xs[64][132];   // 64 rows x 128 k, pad 4

    #pragma unroll
    for (int i = 0; i < 8; ++i) {
        int c = threadIdx.x + i * 256;   // float4 chunk 0..2047
        int r = c >> 5;
        int cc = (c & 31) << 2;
        *(float4*)&xs[r][cc] = *(const float4*)(x + (size_t)r * EMBED + kb + cc);
    }

    float4 acc[8];
    #pragma unroll
    for (int j = 0; j < 8; ++j) acc[j] = make_float4(0.f, 0.f, 0.f, 0.f);
    __syncthreads();

    #pragma unroll 4
    for (int kk = 0; kk < 128; kk += 4) {
        const float* wr = W + (size_t)(kb + kk) * ldW + c4;
        float4 wv0 = *(const float4*)(wr);
        float4 wv1 = *(const float4*)(wr + ldW);
        float4 wv2 = *(const float4*)(wr + 2 * (size_t)ldW);
        float4 wv3 = *(const float4*)(wr + 3 * (size_t)ldW);
        #pragma unroll
        for (int j = 0; j < 8; ++j) {
            float4 xv = *(const float4*)&xs[ty + (j << 3)][kk];
            acc[j].x = fmaf(xv.x, wv0.x, acc[j].x);
            acc[j].y = fmaf(xv.x, wv0.y, acc[j].y);
            acc[j].z = fmaf(xv.x, wv0.z, acc[j].z);
            acc[j].w = fmaf(xv.x, wv0.w, acc[j].w);
            acc[j].x = fmaf(xv.y, wv1.x, acc[j].x);
            acc[j].y = fmaf(xv.y, wv1.y, acc[j].y);
            acc[j].z = fmaf(xv.y, wv1.z, acc[j].z);
            acc[j].w = fmaf(xv.y, wv1.w, acc[j].w);
            acc[j].x = fmaf(xv.z, wv2.x, acc[j].x);
            acc[j].y = fmaf(xv.z, wv2.y, acc[j].y);
            acc[j].z = fmaf(xv.z, wv2.z, acc[j].z);
            acc[j].w = fmaf(xv.z, wv2.w, acc[j].w);
            acc[j].x = fmaf(xv.w, wv3.x, acc[j].x);
            acc[j].y = fmaf(xv.w, wv3.y, acc[j].y);
            acc[j].z = fmaf(xv.w, wv3.z, acc[j].z);
            acc[j].w = fmaf(xv.w, wv3.w, acc[j].w);
        }
    }
    float* dst = kp + (size_t)blockIdx.y * 64 * 2304 + col0 + tx * 4;
    #pragma unroll
    for (int j = 0; j < 8; ++j)
        *(float4*)&dst[(size_t)(ty + (j << 3)) * 2304] = acc[j];
}

// ---------------------------------------------------------------------------
// K1b: reduce 16 k-split partials + bias -> qbuf / knew / vnew.
// grid 144, block 256: one float4 of [64][2304] per thread.
// ---------------------------------------------------------------------------
__launch_bounds__(256)
__global__ void k1b_reduce(const float* __restrict__ kp,
                           const float* __restrict__ bq, const float* __restrict__ bk,
                           const float* __restrict__ bv,
                           float* __restrict__ qbuf, float* __restrict__ knew,
                           float* __restrict__ vnew) {
    const int idx = blockIdx.x * 256 + threadIdx.x;   // 0..36863
    const int r = idx / 576;
    const int c4 = (idx - r * 576) * 4;
    float4 s = make_float4(0.f, 0.f, 0.f, 0.f);
    #pragma unroll
    for (int sp = 0; sp < 16; ++sp) {
        float4 v = *(const float4*)(kp + ((size_t)sp * 64 + r) * 2304 + c4);
        s.x += v.x; s.y += v.y; s.z += v.z; s.w += v.w;
    }
    if (c4 < 2048) {
        float4 b = *(const float4*)(bq + c4);
        s.x += b.x; s.y += b.y; s.z += b.z; s.w += b.w;
        *(float4*)&qbuf[(size_t)r * 2048 + c4] = s;
    } else if (c4 < 2176) {
        float4 b = *(const float4*)(bk + (c4 - 2048));
        s.x += b.x; s.y += b.y; s.z += b.z; s.w += b.w;
        *(float4*)&knew[(size_t)r * 128 + (c4 - 2048)] = s;
    } else {
        float4 b = *(const float4*)(bv + (c4 - 2176));
        s.x += b.x; s.y += b.y; s.z += b.z; s.w += b.w;
        *(float4*)&vnew[(size_t)r * 128 + (c4 - 2176)] = s;
    }
}

// ---------------------------------------------------------------------------
// K2: flash-decode attention partials, register-direct (swapped MFMA operands).
// grid (8 chunks, 64 batches), block 256 (4 waves); wave owns 128 slots.
//   QK^T: D = mfma(A=K, B=q)   -> scores[slot=quad*4+r][head=lm]
//   PV:   O^T = mfma(A=V^T, B=P^T) -> O[d=dt*16+quad*4+r][head=lm]
// K and V fragments load DIRECTLY from global (no LDS staging). Only LDS:
// per-wave P buffer [16][40] bf16 (1.25 KB) for the P lane-transpose.
// Softmax state (m,l,alpha) is one scalar per lane (head = lm).
// ---------------------------------------------------------------------------
__launch_bounds__(256)
__global__ void k2_attn(const float* __restrict__ qbuf,
                        const float* __restrict__ kcache,
                        const float* __restrict__ vcache,
                        const float* __restrict__ knew,
                        const float* __restrict__ vnew,
                        const int* __restrict__ cpos,
                        float* __restrict__ part_o,   // [B][32][16][128]
                        float* __restrict__ part_ml)  // [B][32][16][2]
{
    const int b = blockIdx.y;
    const int chunk = blockIdx.x;      // 0..7
    const int tid = threadIdx.x;
    const int w = tid >> 6;
    const int lane = tid & 63;
    const int quad = lane >> 4;
    const int lm = lane & 15;
    const int pos = cpos[b];

    __shared__ __align__(16) short pts[4][16][40];   // per-wave P [h][slot], 5 KB total
    short (*pt)[40] = pts[w];

    // q B-frag (scaled) + k_new A-frag substitute, straight from global
    const float scale = 0.08838834764831845f;  // 1/sqrt(128)
    short8v bq_[4], knf[4];
    {
        const float* qs = qbuf + (size_t)b * EMBED + lm * HD + quad * 8;
        const float* ks = knew + b * HD + quad * 8;
        #pragma unroll
        for (int t = 0; t < 4; ++t) {
            float4 a = *(const float4*)(qs + t * 32);
            float4 c = *(const float4*)(qs + t * 32 + 4);
            short8v pk;
            pk[0] = f2bf(a.x * scale); pk[1] = f2bf(a.y * scale);
            pk[2] = f2bf(a.z * scale); pk[3] = f2bf(a.w * scale);
            pk[4] = f2bf(c.x * scale); pk[5] = f2bf(c.y * scale);
            pk[6] = f2bf(c.z * scale); pk[7] = f2bf(c.w * scale);
            bq_[t] = pk;
            float4 ka = *(const float4*)(ks + t * 32);
            float4 kc = *(const float4*)(ks + t * 32 + 4);
            short8v pk2;
            pk2[0] = f2bf(ka.x); pk2[1] = f2bf(ka.y);
            pk2[2] = f2bf(ka.z); pk2[3] = f2bf(ka.w);
            pk2[4] = f2bf(kc.x); pk2[5] = f2bf(kc.y);
            pk2[6] = f2bf(kc.z); pk2[7] = f2bf(kc.w);
            knf[t] = pk2;
        }
    }
    // v_new substitute values: one per d-tile (d = dt*16 + lm)
    unsigned short vnbf[8];
    #pragma unroll
    for (int dt = 0; dt < 8; ++dt)
        vnbf[dt] = f2bf(vnew[b * HD + dt * 16 + lm]);

    float m_run = -INFINITY, l_run = 0.f;
    floatx4 oacc[8];
    #pragma unroll
    for (int i = 0; i < 8; ++i) oacc[i] = (floatx4){0.f, 0.f, 0.f, 0.f};

    const int sbase = chunk * 512 + w * 128;

    #pragma unroll 2
    for (int st = 0; st < 4; ++st) {
        const int st0 = sbase + st * 32;
        floatx4 sc[2];
        // ---- QK: K A-frags direct from global, two 16-slot halves
        #pragma unroll
        for (int half = 0; half < 2; ++half) {
            const int s0 = st0 + half * 16;
            const float* kr = kcache + ((size_t)b * S_TOT + s0 + lm) * HD + quad * 8;
            short8v ak[4];
            #pragma unroll
            for (int t = 0; t < 4; ++t) {
                float4 a = *(const float4*)(kr + t * 32);
                float4 c = *(const float4*)(kr + t * 32 + 4);
                short8v pk;
                pk[0] = f2bf(a.x); pk[1] = f2bf(a.y);
                pk[2] = f2bf(a.z); pk[3] = f2bf(a.w);
                pk[4] = f2bf(c.x); pk[5] = f2bf(c.y);
                pk[6] = f2bf(c.z); pk[7] = f2bf(c.w);
                ak[t] = pk;
            }
            const int pr = pos - s0;
            if (pr >= 0 && pr < 16) {        // wave-uniform guard
                if (lm == pr) {              // per-lane select
                    ak[0] = knf[0]; ak[1] = knf[1];
                    ak[2] = knf[2]; ak[3] = knf[3];
                }
            }
            floatx4 s = {0.f, 0.f, 0.f, 0.f};
            #pragma unroll
            for (int t = 0; t < 4; ++t)
                s = __builtin_amdgcn_mfma_f32_16x16x32_bf16(ak[t], bq_[t], s, 0, 0, 0);
            sc[half] = s;
        }
        // ---- online softmax; head = lm, slots = half*16 + quad*4 + r
        float mt = fmaxf(fmaxf(fmaxf(sc[0][0], sc[0][1]), fmaxf(sc[0][2], sc[0][3])),
                         fmaxf(fmaxf(sc[1][0], sc[1][1]), fmaxf(sc[1][2], sc[1][3])));
        mt = fmaxf(mt, __shfl_xor(mt, 16));
        mt = fmaxf(mt, __shfl_xor(mt, 32));
        const float mn = fmaxf(m_run, mt);
        const float alpha = __expf(m_run - mn);
        m_run = mn;
        const float p0 = __expf(sc[0][0] - mn), p1 = __expf(sc[0][1] - mn);
        const float p2 = __expf(sc[0][2] - mn), p3 = __expf(sc[0][3] - mn);
        const float p4 = __expf(sc[1][0] - mn), p5 = __expf(sc[1][1] - mn);
        const float p6 = __expf(sc[1][2] - mn), p7 = __expf(sc[1][3] - mn);
        float ss = ((p0 + p1) + (p2 + p3)) + ((p4 + p5) + (p6 + p7));
        ss += __shfl_xor(ss, 16);
        ss += __shfl_xor(ss, 32);
        l_run = l_run * alpha + ss;
        // ---- P -> LDS (the only LDS traffic): pt[h=lm][slot]
        short4v w0, w1;
        w0[0] = (short)f2bf(p0); w0[1] = (short)f2bf(p1);
        w0[2] = (short)f2bf(p2); w0[3] = (short)f2bf(p3);
        w1[0] = (short)f2bf(p4); w1[1] = (short)f2bf(p5);
        w1[2] = (short)f2bf(p6); w1[3] = (short)f2bf(p7);
        *(short4v*)&pt[lm][quad * 4]      = w0;
        *(short4v*)&pt[lm][16 + quad * 4] = w1;
        // rescale O (alpha is per-lane scalar now)
        #pragma unroll
        for (int dt = 0; dt < 8; ++dt) {
            oacc[dt][0] *= alpha; oacc[dt][1] *= alpha;
            oacc[dt][2] *= alpha; oacc[dt][3] *= alpha;
        }
        // P^T B-frag: P[h=lm][slot=quad*8+j] (same-wave LDS RAW, lgkmcnt ordered)
        short8v ap = *(short8v*)&pt[lm][quad * 8];

        // ---- PV: V^T A-frags direct from global, O^T accumulate
        const int prs = pos - st0;
        const bool dosub = (prs >= 0 && prs < 32);   // wave-uniform
        #pragma unroll
        for (int dt = 0; dt < 8; ++dt) {
            const float* vr = vcache + ((size_t)b * S_TOT + st0 + quad * 8) * HD + dt * 16 + lm;
            float v0 = vr[0 * HD], v1 = vr[1 * HD], v2 = vr[2 * HD], v3 = vr[3 * HD];
            float v4 = vr[4 * HD], v5 = vr[5 * HD], v6 = vr[6 * HD], v7 = vr[7 * HD];
            short8v av;
            av[0] = (short)f2bf(v0); av[1] = (short)f2bf(v1);
            av[2] = (short)f2bf(v2); av[3] = (short)f2bf(v3);
            av[4] = (short)f2bf(v4); av[5] = (short)f2bf(v5);
            av[6] = (short)f2bf(v6); av[7] = (short)f2bf(v7);
            if (dosub) {
                const int jm = prs - quad * 8;       // per-lane (quad)
                if (jm == 0) av[0] = (short)vnbf[dt];
                if (jm == 1) av[1] = (short)vnbf[dt];
                if (jm == 2) av[2] = (short)vnbf[dt];
                if (jm == 3) av[3] = (short)vnbf[dt];
                if (jm == 4) av[4] = (short)vnbf[dt];
                if (jm == 5) av[5] = (short)vnbf[dt];
                if (jm == 6) av[6] = (short)vnbf[dt];
                if (jm == 7) av[7] = (short)vnbf[dt];
            }
            oacc[dt] = __builtin_amdgcn_mfma_f32_16x16x32_bf16(av, ap, oacc[dt], 0, 0, 0);
        }
    }

    // ---- write per-wave partials: O[h=lm][d=dt*16+quad*4+r]
    const int cw = chunk * 4 + w;
    float* po = part_o + (size_t)(b * 32 + cw) * (16 * 128);
    #pragma unroll
    for (int dt = 0; dt < 8; ++dt)
        *(floatx4*)&po[lm * 128 + dt * 16 + quad * 4] = oacc[dt];
    if (quad == 0) {
        float2 ml; ml.x = m_run; ml.y = l_run;
        *(float2*)&part_ml[((size_t)(b * 32 + cw) * 16 + lm) * 2] = ml;
    }
}

// ---------------------------------------------------------------------------
// K3: combine 32 partials per (b,h) -> attn[b][h*128+d]
// grid (16 heads, 64 batches), block 128 (thread = d).
// ---------------------------------------------------------------------------
__launch_bounds__(128)
__global__ void k3_combine(const float* __restrict__ part_o,
                           const float* __restrict__ part_ml,
                           float* __restrict__ attn) {
    const int h = blockIdx.x, b = blockIdx.y, d = threadIdx.x;
    __shared__ float sm[32], sl[32];
    if (threadIdx.x < 32) {
        sm[threadIdx.x] = part_ml[((size_t)(b * 32 + threadIdx.x) * 16 + h) * 2 + 0];
        sl[threadIdx.x] = part_ml[((size_t)(b * 32 + threadIdx.x) * 16 + h) * 2 + 1];
    }
    __syncthreads();
    float M = -INFINITY;
    #pragma unroll
    for (int c = 0; c < 32; ++c) M = fmaxf(M, sm[c]);
    float co[32];
    float L = 0.f;
    #pragma unroll
    for (int c = 0; c < 32; ++c) {
        co[c] = __expf(sm[c] - M);
        L += co[c] * sl[c];
    }
    const float* base = part_o + ((size_t)(b * 32) * 16 + h) * 128 + d;
    float O0 = 0.f, O1 = 0.f, O2 = 0.f, O3 = 0.f;
    #pragma unroll
    for (int c = 0; c < 32; c += 4) {
        O0 += co[c + 0] * base[(size_t)(c + 0) * 2048];
        O1 += co[c + 1] * base[(size_t)(c + 1) * 2048];
        O2 += co[c + 2] * base[(size_t)(c + 2) * 2048];
        O3 += co[c + 3] * base[(size_t)(c + 3) * 2048];
    }
    attn[(size_t)b * EMBED + h * HD + d] = (O0 + O1 + O2 + O3) / L;
}

// ---------------------------------------------------------------------------
// K4: output projection partials. attn @ Wo, M=64, N=2048, K=2048.
// grid (16 n-tiles of 128 cols, 16 k-splits of 128), block 256, 4 cols/thread.
// Non-atomic: writes k4p[split][64][2048]; k4b reduces + bias.
// ---------------------------------------------------------------------------
__launch_bounds__(256)
__global__ void k4_proj(const float* __restrict__ attn,
                        const float* __restrict__ Wo, float* __restrict__ k4p) {
    const int tx = threadIdx.x & 31;
    const int ty = threadIdx.x >> 5;
    const int col0 = blockIdx.x * 128;
    const int kb = blockIdx.y * 128;
    const int c4 = col0 + tx * 4;

    __shared__ __align__(16) float xs[64][132];
    #pragma unroll
    for (int i = 0; i < 8; ++i) {
        int c = threadIdx.x + i * 256;
        int r = c >> 5;
        int cc = (c & 31) << 2;
        *(float4*)&xs[r][cc] = *(const float4*)(attn + (size_t)r * EMBED + kb + cc);
    }

    float4 acc[8];
    #pragma unroll
    for (int j = 0; j < 8; ++j) acc[j] = make_float4(0.f, 0.f, 0.f, 0.f);
    __syncthreads();

    #pragma unroll 4
    for (int kk = 0; kk < 128; kk += 4) {
        const float* wr = Wo + (size_t)(kb + kk) * EMBED + c4;
        float4 wv0 = *(const float4*)(wr);
        float4 wv1 = *(const float4*)(wr + EMBED);
        float4 wv2 = *(const float4*)(wr + 2 * (size_t)EMBED);
        float4 wv3 = *(const float4*)(wr + 3 * (size_t)EMBED);
        #pragma unroll
        for (int j = 0; j < 8; ++j) {
            float4 xv = *(const float4*)&xs[ty + (j << 3)][kk];
            acc[j].x = fmaf(xv.x, wv0.x, acc[j].x);
            acc[j].y = fmaf(xv.x, wv0.y, acc[j].y);
            acc[j].z = fmaf(xv.x, wv0.z, acc[j].z);
            acc[j].w = fmaf(xv.x, wv0.w, acc[j].w);
            acc[j].x = fmaf(xv.y, wv1.x, acc[j].x);
            acc[j].y = fmaf(xv.y, wv1.y, acc[j].y);
            acc[j].z = fmaf(xv.y, wv1.z, acc[j].z);
            acc[j].w = fmaf(xv.y, wv1.w, acc[j].w);
            acc[j].x = fmaf(xv.z, wv2.x, acc[j].x);
            acc[j].y = fmaf(xv.z, wv2.y, acc[j].y);
            acc[j].z = fmaf(xv.z, wv2.z, acc[j].z);
            acc[j].w = fmaf(xv.z, wv2.w, acc[j].w);
            acc[j].x = fmaf(xv.w, wv3.x, acc[j].x);
            acc[j].y = fmaf(xv.w, wv3.y, acc[j].y);
            acc[j].z = fmaf(xv.w, wv3.z, acc[j].z);
            acc[j].w = fmaf(xv.w, wv3.w, acc[j].w);
        }
    }
    float* dst = k4p + (size_t)blockIdx.y * 64 * 2048 + c4;
    #pragma unroll
    for (int j = 0; j < 8; ++j)
        *(float4*)&dst[(size_t)(ty + (j << 3)) * 2048] = acc[j];
}

// ---------------------------------------------------------------------------
// K4b: reduce 16 k-split partials + bo -> out. grid 128, block 256.
// ---------------------------------------------------------------------------
__launch_bounds__(256)
__global__ void k4b_reduce(const float* __restrict__ k4p,
                           const float* __restrict__ bo, float* __restrict__ out) {
    const int idx = blockIdx.x * 256 + threadIdx.x;   // 0..32767
    const int r = idx >> 9;           // / 512 float4s per row
    const int c4 = (idx & 511) * 4;
    float4 s = make_float4(0.f, 0.f, 0.f, 0.f);
    #pragma unroll
    for (int sp = 0; sp < 16; ++sp) {
        float4 v = *(const float4*)(k4p + ((size_t)sp * 64 + r) * 2048 + c4);
        s.x += v.x; s.y += v.y; s.z += v.z; s.w += v.w;
    }
    float4 b = *(const float4*)(bo + c4);
    s.x += b.x; s.y += b.y; s.z += b.z; s.w += b.w;
    *(float4*)&out[(size_t)r * 2048 + c4] = s;
}

// ---------------------------------------------------------------------------
extern "C" void kernel_launch(void* const* d_in, const int* in_sizes, int n_in,
                              void* d_out, int out_size, void* d_ws, size_t ws_size,
                              hipStream_t stream) {
    (void)in_sizes; (void)n_in; (void)out_size; (void)ws_size;
    const float* x  = (const float*)d_in[0];
    const float* kc = (const float*)d_in[1];
    const float* vc = (const float*)d_in[2];
    const int*   cp = (const int*)d_in[3];
    const float* Wq = (const float*)d_in[4];
    const float* bq = (const float*)d_in[5];
    const float* Wk = (const float*)d_in[6];
    const float* bk = (const float*)d_in[7];
    const float* Wv = (const float*)d_in[8];
    const float* bv = (const float*)d_in[9];
    const float* Wo = (const float*)d_in[10];
    const float* bo = (const float*)d_in[11];
    float* out = (float*)d_out;
    float* ws  = (float*)d_ws;

    // ws layout (floats), total 4538368 = 18.15 MB (same footprint as before).
    // 'big' is time-shared: k1 partials (2359296) -> part_o (4194304) -> k4
    // partials (2097152); all uses are stream-serialized.
    float* qbuf = ws;                    // 131072
    float* knew = ws + 131072;           // 8192
    float* vnew = ws + 139264;           // 8192
    float* attn = ws + 147456;           // 131072
    float* pml  = ws + 278528;           // 65536
    float* big  = ws + 344064;           // 4194304

    k1_qkv<<<dim3(18, 16), 256, 0, stream>>>(x, Wq, Wk, Wv, big);
    k1b_reduce<<<dim3(144), 256, 0, stream>>>(big, bq, bk, bv, qbuf, knew, vnew);
    k2_attn<<<dim3(8, 64), 256, 0, stream>>>(qbuf, kc, vc, knew, vnew, cp, big, pml);
    k3_combine<<<dim3(16, 64), 128, 0, stream>>>(big, pml, attn);
    k4_proj<<<dim3(16, 16), 256, 0, stream>>>(attn, Wo, big);
    k4b_reduce<<<dim3(128), 256, 0, stream>>>(big, bo, out);
}